// Round 5
// baseline (71.212 us; speedup 1.0000x reference)
//
#include <hip/hip_runtime.h>
#include <math.h>

#define SIZE 128
#define BATCH 64
#define STEEP 10.0f
#define NLP 64   // layer-pairs (128 layers)

typedef float v2f __attribute__((ext_vector_type(2)));

__device__ __forceinline__ v2f v2bc(float s) { return (v2f){s, s}; }
__device__ __forceinline__ v2f v2fma(v2f a, v2f b, v2f c) {
    return __builtin_elementwise_fma(a, b, c);
}

// DPP lane move (verified prior sessions): 0x130=wave_shl:1 (lane i <- i+1),
// 0x138=wave_shr:1 (lane i <- i-1). bound_ctrl=false: invalid edge lanes keep
// their old value (always masked off or neutralized by alpha=1.0 pads below).
template<int CTRL>
__device__ __forceinline__ float dpp_mov(float x) {
    return __int_as_float(__builtin_amdgcn_update_dpp(
        __float_as_int(x), __float_as_int(x), CTRL, 0xf, 0xf, false));
}

// alpha = atan(STEEP*delta)/pi + 0.5. Estrin minimax poly (1/pi folded in),
// v_rcp range reduction, copysign fold. err ~1e-6 (absmax 3.9e-3 vs 3.6e-2
// threshold, validated across all prior rounds).
__device__ __forceinline__ float alpha_from_delta(float delta) {
    const float C0 =  0.31830265f;
    const float C1 = -0.10587730f;
    const float C2 =  0.06160680f;
    const float C3 = -0.03706173f;
    const float C4 =  0.01676007f;
    const float C5 = -0.00373098f;
    float t  = STEEP * delta;
    float at = fabsf(t);
    bool inv = at > 1.0f;
    float z  = inv ? __builtin_amdgcn_rcpf(at) : at;
    float z2 = z * z, z4 = z2 * z2;
    float p0 = fmaf(C1, z2, C0);
    float p1 = fmaf(C3, z2, C2);
    float p2 = fmaf(C5, z2, C4);
    float q  = fmaf(fmaf(p2, z4, p1), z4, p0) * z;
    float r  = inv ? 0.5f - q : q;
    return 0.5f + copysignf(r, t);
}

// R4 structure (R3 + row-coverage fix): fully-independent waves — NO
// producer/consumer split, NO LDS, NO barriers. Lane i owns the chain pair
// (2i, 2i+1) AND the X columns 2i, 2i+1 for 4 rows (two v2f-packed
// row-pairs). The alphas each lane needs are computed in-lane by the chain;
// odd-layer cross-column values come from the same DPP neighbor moves the
// chain already uses. X-update work fills the chain's dependency-stall
// cycles within the wave.
//
// Coverage check (R3 bug): rows/batch = blocks_per_batch(8) x waves(4) x
// rows_per_wave(4) = 128 = SIZE. OK.
// 64 batches x 32 row-groups = 2048 waves = 512 blocks x 256 threads
// -> 2 blocks/CU, 2 waves/SIMD (cross-wave latency hiding on top of ILP).
__global__ __launch_bounds__(256) void soft_sort_cols(
    const float* __restrict__ vec, float* __restrict__ out)
{
    const int tid   = threadIdx.x;
    const int lane  = tid & 63;
    const int wave  = tid >> 6;
    const int batch = blockIdx.x >> 3;
    const int oct   = blockIdx.x & 7;
    const int rg    = oct * 4 + wave;    // row-group [0,32): rows 4rg..4rg+3
    const int row0  = rg * 4;

    // ---- chain state: x[2i], x[2i+1] ----
    const int c0i = 2 * lane;
    const float2 xv = *reinterpret_cast<const float2*>(vec + batch * SIZE + c0i);
    float xa = xv.x, xb = xv.y;
    const bool hasR = (lane < 63);
    const bool hasL = (lane > 0);

    // ---- X state: cA = col 2i, cB = col 2i+1, for row-pairs (row0,row0+1),
    //      (row0+2,row0+3); .x = even row, .y = odd row. Init = identity.
    v2f cA[2], cB[2];
#pragma unroll
    for (int p = 0; p < 2; ++p) {
        cA[p] = (v2f){ (row0 + 2 * p     == c0i) ? 1.0f : 0.0f,
                       (row0 + 2 * p + 1 == c0i) ? 1.0f : 0.0f };
        cB[p] = (v2f){ (row0 + 2 * p     == c0i + 1) ? 1.0f : 0.0f,
                       (row0 + 2 * p + 1 == c0i + 1) ? 1.0f : 0.0f };
    }

#pragma unroll 4
    for (int j = 0; j < NLP; ++j) {
        // ======== even layer: pairs (2i, 2i+1) — fully in-lane ========
        const float d  = xb - xa;
        const float ae = alpha_from_delta(d);
        const float nxa0 = fmaf(-ae, d, xb);   // new x[2i]
        const float nxb0 = fmaf( ae, d, xa);   // new x[2i+1]
        // X even: colA' = ae*A + (1-ae)*B ; colB' = (1-ae)*A + ae*B
#pragma unroll
        for (int p = 0; p < 2; ++p) {
            const v2f A = cA[p], B = cB[p], dd = A - B;
            cA[p] = v2fma(v2bc(ae),  dd, B);
            cB[p] = v2fma(v2bc(-ae), dd, A);
        }
        // ======== odd layer: pairs (2i+1, 2i+2) ========
        const float xnext = dpp_mov<0x130>(nxa0);          // x[2i+2] (post-even)
        float ao = alpha_from_delta(xnext - nxb0);
        ao = hasR ? ao : 1.0f;                             // pair 63 pad -> identity
        float aoL = dpp_mov<0x138>(ao);                    // left pair's alpha
        aoL = hasL ? aoL : 1.0f;
        const float xprev = dpp_mov<0x138>(nxb0);          // x[2i-1] (post-even)
        xb = fmaf(ao,  nxb0 - xnext, xnext);
        xa = fmaf(aoL, nxa0 - xprev, xprev);
        // X odd: col 2i+1 ('a' of right pair) mixes with right-neighbor col
        // 2i+2; col 2i ('b' of left pair) mixes with left-neighbor col 2i-1.
        // fma(1.0, V - nb, nb) ~= V (error ~ulp; validated pattern) -> edge
        // pads are no-ops.
#pragma unroll
        for (int p = 0; p < 2; ++p) {
            v2f nb, pb;
            nb.x = dpp_mov<0x130>(cA[p].x);
            nb.y = dpp_mov<0x130>(cA[p].y);
            pb.x = dpp_mov<0x138>(cB[p].x);
            pb.y = dpp_mov<0x138>(cB[p].y);
            cB[p] = v2fma(v2bc(ao),  cB[p] - nb, nb);
            cA[p] = v2fma(v2bc(aoL), cA[p] - pb, pb);
        }
    }

    // ---- write sorted x (one wave per batch) ----
    if (oct == 0 && wave == 0)
        *reinterpret_cast<float2*>(out + batch * SIZE + c0i) = make_float2(xa, xb);

    // ---- write X: 4 rows x 2 contiguous cols per lane (coalesced float2) ----
    float* __restrict__ Xb = out + BATCH * SIZE + (size_t)batch * SIZE * SIZE;
#pragma unroll
    for (int p = 0; p < 2; ++p) {
        const int r0 = row0 + 2 * p;
        *reinterpret_cast<float2*>(Xb + (size_t)r0 * SIZE + c0i) =
            make_float2(cA[p].x, cB[p].x);
        *reinterpret_cast<float2*>(Xb + (size_t)(r0 + 1) * SIZE + c0i) =
            make_float2(cA[p].y, cB[p].y);
    }
}

extern "C" void kernel_launch(void* const* d_in, const int* in_sizes, int n_in,
                              void* d_out, int out_size, void* d_ws, size_t ws_size,
                              hipStream_t stream) {
    const float* vec = (const float*)d_in[0];
    float* out = (float*)d_out;
    (void)in_sizes; (void)n_in; (void)d_ws; (void)ws_size; (void)out_size;

    hipLaunchKernelGGL(soft_sort_cols, dim3(BATCH * 8), dim3(256), 0, stream,
                       vec, out);
}

// Round 6
// 66.749 us; speedup vs baseline: 1.0669x; 1.0669x over previous
//
#include <hip/hip_runtime.h>
#include <math.h>

#define SIZE 128
#define BATCH 64
#define STEEP 10.0f
#define NLP 64   // layer-pairs (128 layers)

typedef float v2f __attribute__((ext_vector_type(2)));

__device__ __forceinline__ v2f v2bc(float s) { return (v2f){s, s}; }
__device__ __forceinline__ v2f v2fma(v2f a, v2f b, v2f c) {
    return __builtin_elementwise_fma(a, b, c);
}

// DPP lane move (verified prior sessions): 0x130=wave_shl:1 (lane i <- i+1),
// 0x138=wave_shr:1 (lane i <- i-1). bound_ctrl=false: invalid edge lanes keep
// their old value (always masked off or neutralized by alpha=1.0 pads below).
template<int CTRL>
__device__ __forceinline__ float dpp_mov(float x) {
    return __int_as_float(__builtin_amdgcn_update_dpp(
        __float_as_int(x), __float_as_int(x), CTRL, 0xf, 0xf, false));
}

// alpha = atan(STEEP*delta)/pi + 0.5. Estrin minimax poly (1/pi folded in),
// v_rcp range reduction, copysign fold. err ~1e-6 (absmax 3.9e-3 vs 3.6e-2
// threshold, validated across all prior rounds).
__device__ __forceinline__ float alpha_from_delta(float delta) {
    const float C0 =  0.31830265f;
    const float C1 = -0.10587730f;
    const float C2 =  0.06160680f;
    const float C3 = -0.03706173f;
    const float C4 =  0.01676007f;
    const float C5 = -0.00373098f;
    float t  = STEEP * delta;
    float at = fabsf(t);
    bool inv = at > 1.0f;
    float z  = inv ? __builtin_amdgcn_rcpf(at) : at;
    float z2 = z * z, z4 = z2 * z2;
    float p0 = fmaf(C1, z2, C0);
    float p1 = fmaf(C3, z2, C2);
    float p2 = fmaf(C5, z2, C4);
    float q  = fmaf(fmaf(p2, z4, p1), z4, p0) * z;
    float r  = inv ? 0.5f - q : q;
    return 0.5f + copysignf(r, t);
}

// R6 structure: R5's barrier-free independent waves, but 8 rows/wave (4
// v2f row-pairs) instead of 4 -> chain replicated 16x/batch instead of 32x.
// R5 post-mortem: these kernels are ISSUE-bound; per-SIMD issued
// instructions are the cost metric. Per-wave per layer-pair: chain 40 +
// 4 row-pairs x 11 = 84 insts -> 168 issue-cyc/lp/SIMD vs R5's 240.
// 1024 waves = 256 blocks x 256 threads = 1 wave/SIMD exactly; chain dep
// stalls hidden by in-wave X ILP (88 cyc independent work/lp) + unroll-4
// cross-iteration pipelining.
//
// Coverage: rows/batch = 4 blocks x 4 waves x 8 rows = 128 = SIZE. OK.
__global__ __launch_bounds__(256) void soft_sort_cols(
    const float* __restrict__ vec, float* __restrict__ out)
{
    const int tid   = threadIdx.x;
    const int lane  = tid & 63;
    const int wave  = tid >> 6;
    const int batch = blockIdx.x >> 2;
    const int quad  = blockIdx.x & 3;
    const int rg    = quad * 4 + wave;   // row-group [0,16): rows 8rg..8rg+7
    const int row0  = rg * 8;

    // ---- chain state: x[2i], x[2i+1] ----
    const int c0i = 2 * lane;
    const float2 xv = *reinterpret_cast<const float2*>(vec + batch * SIZE + c0i);
    float xa = xv.x, xb = xv.y;
    const bool hasR = (lane < 63);
    const bool hasL = (lane > 0);

    // ---- X state: cA = col 2i, cB = col 2i+1, for row-pairs
    //      (row0+2p, row0+2p+1), p=0..3; .x = even row, .y = odd row.
    v2f cA[4], cB[4];
#pragma unroll
    for (int p = 0; p < 4; ++p) {
        cA[p] = (v2f){ (row0 + 2 * p     == c0i) ? 1.0f : 0.0f,
                       (row0 + 2 * p + 1 == c0i) ? 1.0f : 0.0f };
        cB[p] = (v2f){ (row0 + 2 * p     == c0i + 1) ? 1.0f : 0.0f,
                       (row0 + 2 * p + 1 == c0i + 1) ? 1.0f : 0.0f };
    }

#pragma unroll 4
    for (int j = 0; j < NLP; ++j) {
        // ======== even layer: pairs (2i, 2i+1) — fully in-lane ========
        const float d  = xb - xa;
        const float ae = alpha_from_delta(d);
        const float nxa0 = fmaf(-ae, d, xb);   // new x[2i]
        const float nxb0 = fmaf( ae, d, xa);   // new x[2i+1]
        // X even: colA' = ae*A + (1-ae)*B ; colB' = (1-ae)*A + ae*B
#pragma unroll
        for (int p = 0; p < 4; ++p) {
            const v2f A = cA[p], B = cB[p], dd = A - B;
            cA[p] = v2fma(v2bc(ae),  dd, B);
            cB[p] = v2fma(v2bc(-ae), dd, A);
        }
        // ======== odd layer: pairs (2i+1, 2i+2) ========
        const float xnext = dpp_mov<0x130>(nxa0);          // x[2i+2] (post-even)
        float ao = alpha_from_delta(xnext - nxb0);
        ao = hasR ? ao : 1.0f;                             // pair 63 pad -> identity
        float aoL = dpp_mov<0x138>(ao);                    // left pair's alpha
        aoL = hasL ? aoL : 1.0f;
        const float xprev = dpp_mov<0x138>(nxb0);          // x[2i-1] (post-even)
        xb = fmaf(ao,  nxb0 - xnext, xnext);
        xa = fmaf(aoL, nxa0 - xprev, xprev);
        // X odd: col 2i+1 ('a' of right pair) mixes with right-neighbor col
        // 2i+2; col 2i ('b' of left pair) mixes with left-neighbor col 2i-1.
        // Edge lanes see alpha==1.0 pads -> no-ops (validated pattern).
#pragma unroll
        for (int p = 0; p < 4; ++p) {
            v2f nb, pb;
            nb.x = dpp_mov<0x130>(cA[p].x);
            nb.y = dpp_mov<0x130>(cA[p].y);
            pb.x = dpp_mov<0x138>(cB[p].x);
            pb.y = dpp_mov<0x138>(cB[p].y);
            cB[p] = v2fma(v2bc(ao),  cB[p] - nb, nb);
            cA[p] = v2fma(v2bc(aoL), cA[p] - pb, pb);
        }
    }

    // ---- write sorted x (one wave per batch) ----
    if (quad == 0 && wave == 0)
        *reinterpret_cast<float2*>(out + batch * SIZE + c0i) = make_float2(xa, xb);

    // ---- write X: 8 rows x 2 contiguous cols per lane (coalesced float2) ----
    float* __restrict__ Xb = out + BATCH * SIZE + (size_t)batch * SIZE * SIZE;
#pragma unroll
    for (int p = 0; p < 4; ++p) {
        const int r0 = row0 + 2 * p;
        *reinterpret_cast<float2*>(Xb + (size_t)r0 * SIZE + c0i) =
            make_float2(cA[p].x, cB[p].x);
        *reinterpret_cast<float2*>(Xb + (size_t)(r0 + 1) * SIZE + c0i) =
            make_float2(cA[p].y, cB[p].y);
    }
}

extern "C" void kernel_launch(void* const* d_in, const int* in_sizes, int n_in,
                              void* d_out, int out_size, void* d_ws, size_t ws_size,
                              hipStream_t stream) {
    const float* vec = (const float*)d_in[0];
    float* out = (float*)d_out;
    (void)in_sizes; (void)n_in; (void)d_ws; (void)ws_size; (void)out_size;

    hipLaunchKernelGGL(soft_sort_cols, dim3(BATCH * 4), dim3(256), 0, stream,
                       vec, out);
}

// Round 7
// 65.822 us; speedup vs baseline: 1.0819x; 1.0141x over previous
//
#include <hip/hip_runtime.h>
#include <math.h>

#define SIZE 128
#define BATCH 64
#define STEEP 10.0f
#define NLP 64   // layer-pairs (128 layers)

typedef float v2f __attribute__((ext_vector_type(2)));

__device__ __forceinline__ v2f v2bc(float s) { return (v2f){s, s}; }
__device__ __forceinline__ v2f v2fma(v2f a, v2f b, v2f c) {
    return __builtin_elementwise_fma(a, b, c);
}

// DPP lane move (verified prior sessions): 0x130=wave_shl:1 (lane i <- i+1),
// 0x138=wave_shr:1 (lane i <- i-1). bound_ctrl=false: invalid edge lanes take
// the OLD operand — used deliberately as the edge fallback (R7: replaces the
// explicit cndmask pads; lane-0/lane-63 cases become free).
template<int CTRL>
__device__ __forceinline__ float dpp_upd(float old, float src) {
    return __int_as_float(__builtin_amdgcn_update_dpp(
        __float_as_int(old), __float_as_int(src), CTRL, 0xf, 0xf, false));
}
template<int CTRL>
__device__ __forceinline__ float dpp_mov(float x) { return dpp_upd<CTRL>(x, x); }

// alpha = atan(STEEP*delta)/pi + 0.5. Estrin minimax poly (1/pi folded in),
// v_rcp range reduction, copysign fold. err ~1e-6 (absmax 3.9e-3 = bf16
// quantization floor, validated across all prior rounds). DO NOT cheapen:
// numerics validated; absmax must stay exactly 0.00390625.
__device__ __forceinline__ float alpha_from_delta(float delta) {
    const float C0 =  0.31830265f;
    const float C1 = -0.10587730f;
    const float C2 =  0.06160680f;
    const float C3 = -0.03706173f;
    const float C4 =  0.01676007f;
    const float C5 = -0.00373098f;
    float t  = STEEP * delta;
    float at = fabsf(t);
    bool inv = at > 1.0f;
    float z  = inv ? __builtin_amdgcn_rcpf(at) : at;
    float z2 = z * z, z4 = z2 * z2;
    float p0 = fmaf(C1, z2, C0);
    float p1 = fmaf(C3, z2, C2);
    float p2 = fmaf(C5, z2, C4);
    float q  = fmaf(fmaf(p2, z4, p1), z4, p0) * z;
    float r  = inv ? 0.5f - q : q;
    return 0.5f + copysignf(r, t);
}

// R7 = R6 structure (barrier-free independent waves, 8 rows/wave, 1024 waves
// = 1 wave/SIMD) + instruction/dep-chain bundle:
//  - update_dpp old-operand edge fallback (no cndmask pads; aoL eliminated)
//  - X-odd: compute both pair outputs in the left lane, shift one right
//    (7 insts/row-pair vs 8) — bit-identical fma rewrites
//  - launch_bounds(256,1) + unroll 8 for scheduling freedom
// Coverage: rows/batch = 4 blocks x 4 waves x 8 rows = 128 = SIZE. OK.
__global__ __launch_bounds__(256, 1) void soft_sort_cols(
    const float* __restrict__ vec, float* __restrict__ out)
{
    const int tid   = threadIdx.x;
    const int lane  = tid & 63;
    const int wave  = tid >> 6;
    const int batch = blockIdx.x >> 2;
    const int quad  = blockIdx.x & 3;
    const int rg    = quad * 4 + wave;   // row-group [0,16): rows 8rg..8rg+7
    const int row0  = rg * 8;

    // ---- chain state: x[2i], x[2i+1] ----
    const int c0i = 2 * lane;
    const float2 xv = *reinterpret_cast<const float2*>(vec + batch * SIZE + c0i);
    float xa = xv.x, xb = xv.y;
    const bool hasR = (lane < 63);

    // ---- X state: cA = col 2i, cB = col 2i+1, for row-pairs
    //      (row0+2p, row0+2p+1), p=0..3; .x = even row, .y = odd row.
    v2f cA[4], cB[4];
#pragma unroll
    for (int p = 0; p < 4; ++p) {
        cA[p] = (v2f){ (row0 + 2 * p     == c0i) ? 1.0f : 0.0f,
                       (row0 + 2 * p + 1 == c0i) ? 1.0f : 0.0f };
        cB[p] = (v2f){ (row0 + 2 * p     == c0i + 1) ? 1.0f : 0.0f,
                       (row0 + 2 * p + 1 == c0i + 1) ? 1.0f : 0.0f };
    }

#pragma unroll 8
    for (int j = 0; j < NLP; ++j) {
        // ======== even layer: pairs (2i, 2i+1) — fully in-lane ========
        const float d  = xb - xa;
        const float ae = alpha_from_delta(d);
        const float nxa0 = fmaf(-ae, d, xb);   // new x[2i]
        const float nxb0 = fmaf( ae, d, xa);   // new x[2i+1]
        // X even: colA' = ae*A + (1-ae)*B ; colB' = (1-ae)*A + ae*B
#pragma unroll
        for (int p = 0; p < 4; ++p) {
            const v2f A = cA[p], B = cB[p], dd = A - B;
            cA[p] = v2fma(v2bc(ae),  dd, B);
            cB[p] = v2fma(v2bc(-ae), dd, A);
        }
        // ======== odd layer: pairs (2i+1, 2i+2) ========
        // Left lane computes BOTH outputs of its pair (a=x[2i+1]=nxb0,
        // b=x[2i+2]=right's nxa0), then ships b' one lane right.
        const float xnext = dpp_mov<0x130>(nxa0);      // b (lane63: own, masked by ao=1)
        const float diff  = xnext - nxb0;              // b - a
        float ao = alpha_from_delta(diff);
        ao = hasR ? ao : 1.0f;                         // pair 63 pad -> identity
        xb = fmaf(-ao, diff, xnext);                   // a' = ao*a+(1-ao)*b (=nxb0 @63)
        const float tb = fmaf(ao, diff, nxb0);         // b' = (1-ao)*a+ao*b
        xa = dpp_upd<0x138>(nxa0, tb);                 // lane i <- lane i-1's b';
                                                       // lane 0 keeps nxa0 (col 0 untouched)
        // X odd (same trick per row-pair): a=cB (col 2i+1), b=right's cA (col 2i+2)
#pragma unroll
        for (int p = 0; p < 4; ++p) {
            v2f nbA, ddp, tA;
            nbA.x = dpp_mov<0x130>(cA[p].x);           // b (lane63 garbage, masked by ao=1)
            nbA.y = dpp_mov<0x130>(cA[p].y);
            ddp   = nbA - cB[p];                       // b - a
            tA    = v2fma(v2bc(ao), ddp, cB[p]);       // b' = (1-ao)*a+ao*b
            cB[p] = v2fma(v2bc(-ao), ddp, nbA);        // a' = ao*a+(1-ao)*b
            cA[p].x = dpp_upd<0x138>(cA[p].x, tA.x);   // ship b' right; lane 0 keeps cA
            cA[p].y = dpp_upd<0x138>(cA[p].y, tA.y);
        }
    }

    // ---- write sorted x (one wave per batch) ----
    if (quad == 0 && wave == 0)
        *reinterpret_cast<float2*>(out + batch * SIZE + c0i) = make_float2(xa, xb);

    // ---- write X: 8 rows x 2 contiguous cols per lane (coalesced float2) ----
    float* __restrict__ Xb = out + BATCH * SIZE + (size_t)batch * SIZE * SIZE;
#pragma unroll
    for (int p = 0; p < 4; ++p) {
        const int r0 = row0 + 2 * p;
        *reinterpret_cast<float2*>(Xb + (size_t)r0 * SIZE + c0i) =
            make_float2(cA[p].x, cB[p].x);
        *reinterpret_cast<float2*>(Xb + (size_t)(r0 + 1) * SIZE + c0i) =
            make_float2(cA[p].y, cB[p].y);
    }
}

extern "C" void kernel_launch(void* const* d_in, const int* in_sizes, int n_in,
                              void* d_out, int out_size, void* d_ws, size_t ws_size,
                              hipStream_t stream) {
    const float* vec = (const float*)d_in[0];
    float* out = (float*)d_out;
    (void)in_sizes; (void)n_in; (void)d_ws; (void)ws_size; (void)out_size;

    hipLaunchKernelGGL(soft_sort_cols, dim3(BATCH * 4), dim3(256), 0, stream,
                       vec, out);
}

// Round 8
// 65.490 us; speedup vs baseline: 1.0874x; 1.0051x over previous
//
#include <hip/hip_runtime.h>
#include <math.h>

#define SIZE 128
#define BATCH 64
#define STEEP 10.0f
#define NLP 64   // layer-pairs (128 layers)

typedef float v2f __attribute__((ext_vector_type(2)));

__device__ __forceinline__ v2f v2bc(float s) { return (v2f){s, s}; }

// R8: guaranteed packed fma — VOP3P v_pk_fma_f32 (default op_sel_hi = packed
// lo*lo/hi*hi semantics). Bit-identical to two IEEE fmas. Inline asm because
// __builtin_elementwise_fma on v2f may scalarize (suspect for the measured
// ~2.4x issue inflation).
__device__ __forceinline__ v2f pk_fma(v2f a, v2f b, v2f c) {
    v2f d;
    asm("v_pk_fma_f32 %0, %1, %2, %3" : "=v"(d) : "v"(a), "v"(b), "v"(c));
    return d;
}

// DPP lane move (verified prior sessions): 0x130=wave_shl:1 (lane i <- i+1),
// 0x138=wave_shr:1 (lane i <- i-1). bound_ctrl=false: invalid edge lanes take
// the OLD operand — used deliberately as the edge fallback (lane-0/lane-63
// cases free; validated R7).
template<int CTRL>
__device__ __forceinline__ float dpp_upd(float old, float src) {
    return __int_as_float(__builtin_amdgcn_update_dpp(
        __float_as_int(old), __float_as_int(src), CTRL, 0xf, 0xf, false));
}
template<int CTRL>
__device__ __forceinline__ float dpp_mov(float x) { return dpp_upd<CTRL>(x, x); }

// alpha = atan(STEEP*delta)/pi + 0.5. Estrin minimax poly (1/pi folded in),
// v_rcp range reduction, copysign fold. err ~1e-6 (absmax 3.9e-3 = bf16
// quantization floor, validated across all prior rounds). DO NOT cheapen.
__device__ __forceinline__ float alpha_from_delta(float delta) {
    const float C0 =  0.31830265f;
    const float C1 = -0.10587730f;
    const float C2 =  0.06160680f;
    const float C3 = -0.03706173f;
    const float C4 =  0.01676007f;
    const float C5 = -0.00373098f;
    float t  = STEEP * delta;
    float at = fabsf(t);
    bool inv = at > 1.0f;
    float z  = inv ? __builtin_amdgcn_rcpf(at) : at;
    float z2 = z * z, z4 = z2 * z2;
    float p0 = fmaf(C1, z2, C0);
    float p1 = fmaf(C3, z2, C2);
    float p2 = fmaf(C5, z2, C4);
    float q  = fmaf(fmaf(p2, z4, p1), z4, p0) * z;
    float r  = inv ? 0.5f - q : q;
    return 0.5f + copysignf(r, t);
}

// R8 = R7 structure (barrier-free independent waves, 8 rows/wave, 1024 waves
// = 1 wave/SIMD, forced-minimal chain replication) + inflation attack:
//  - inline-asm v_pk_fma_f32 (guaranteed packed X updates)
//  - explicit software pipeline: chain(j+1) hoisted between X-even(j) and
//    X-odd(j) — X-odd needs ao (chain tail); chain(j+1) only needs xa/xb
//    (ready earlier) -> scheduler can overlay X work on the chain dep path
//  - X-odd DPPs batched (reads / packed ALU / ships) to kill hazard nops
// Coverage: rows/batch = 4 blocks x 4 waves x 8 rows = 128 = SIZE. OK.
__global__ __launch_bounds__(256, 1) void soft_sort_cols(
    const float* __restrict__ vec, float* __restrict__ out)
{
    const int tid   = threadIdx.x;
    const int lane  = tid & 63;
    const int wave  = tid >> 6;
    const int batch = blockIdx.x >> 2;
    const int quad  = blockIdx.x & 3;
    const int rg    = quad * 4 + wave;   // row-group [0,16): rows 8rg..8rg+7
    const int row0  = rg * 8;

    // ---- chain state: x[2i], x[2i+1] ----
    const int c0i = 2 * lane;
    const float2 xv = *reinterpret_cast<const float2*>(vec + batch * SIZE + c0i);
    float xa = xv.x, xb = xv.y;
    const bool hasR = (lane < 63);

    // ---- X state: cA = col 2i, cB = col 2i+1, for row-pairs
    //      (row0+2p, row0+2p+1), p=0..3; .x = even row, .y = odd row.
    v2f cA[4], cB[4];
#pragma unroll
    for (int p = 0; p < 4; ++p) {
        cA[p] = (v2f){ (row0 + 2 * p     == c0i) ? 1.0f : 0.0f,
                       (row0 + 2 * p + 1 == c0i) ? 1.0f : 0.0f };
        cB[p] = (v2f){ (row0 + 2 * p     == c0i + 1) ? 1.0f : 0.0f,
                       (row0 + 2 * p + 1 == c0i + 1) ? 1.0f : 0.0f };
    }

    // ---- one chain layer-pair: advances xa/xb, emits (ae, ao) ----
    auto chain_step = [&](float& ae_o, float& ao_o) {
        const float d  = xb - xa;
        const float ae = alpha_from_delta(d);
        const float nxa0 = fmaf(-ae, d, xb);       // new x[2i]
        const float nxb0 = fmaf( ae, d, xa);       // new x[2i+1]
        const float xnext = dpp_mov<0x130>(nxa0);  // lane63: own (masked by ao=1)
        const float diff  = xnext - nxb0;
        float ao = alpha_from_delta(diff);
        ao = hasR ? ao : 1.0f;                     // pair 63 pad -> identity
        xb = fmaf(-ao, diff, xnext);               // a'
        const float tb = fmaf(ao, diff, nxb0);     // b' -> ship right
        xa = dpp_upd<0x138>(nxa0, tb);             // lane0 keeps nxa0 (col 0 untouched)
        ae_o = ae; ao_o = ao;
    };

    // ---- X even layer (pairs 2i,2i+1 in-lane) ----
    auto x_even = [&](float ae) {
        const v2f aev = v2bc(ae), naev = v2bc(-ae);
#pragma unroll
        for (int p = 0; p < 4; ++p) {
            const v2f A = cA[p], B = cB[p], dd = A - B;
            cA[p] = pk_fma(aev,  dd, B);
            cB[p] = pk_fma(naev, dd, A);
        }
    };

    // ---- X odd layer (pairs 2i+1,2i+2; left lane computes both, ships b')
    //      DPPs batched: reads / packed ALU / ships ----
    auto x_odd = [&](float ao) {
        const v2f aov = v2bc(ao), naov = v2bc(-ao);
        v2f nbA[4], tA[4];
#pragma unroll
        for (int p = 0; p < 4; ++p) {                  // neighbor reads
            nbA[p].x = dpp_mov<0x130>(cA[p].x);        // lane63 garbage, masked ao=1
            nbA[p].y = dpp_mov<0x130>(cA[p].y);
        }
#pragma unroll
        for (int p = 0; p < 4; ++p) {                  // packed ALU
            const v2f ddp = nbA[p] - cB[p];
            tA[p] = pk_fma(aov,  ddp, cB[p]);          // b' (ship right)
            cB[p] = pk_fma(naov, ddp, nbA[p]);         // a'
        }
#pragma unroll
        for (int p = 0; p < 4; ++p) {                  // ships; lane0 keeps cA
            cA[p].x = dpp_upd<0x138>(cA[p].x, tA[p].x);
            cA[p].y = dpp_upd<0x138>(cA[p].y, tA[p].y);
        }
    };

    // ---- software-pipelined main loop: chain runs one lp ahead of X-odd ----
    float ae, ao;
    chain_step(ae, ao);                    // lp 0
#pragma unroll 7
    for (int j = 0; j < NLP - 1; ++j) {    // 63 iterations
        x_even(ae);
        float ae_n, ao_n;
        chain_step(ae_n, ao_n);            // lp j+1 overlays X work below/above
        x_odd(ao);
        ae = ae_n; ao = ao_n;
    }
    x_even(ae);                            // lp 63 epilogue
    x_odd(ao);

    // ---- write sorted x (one wave per batch) ----
    if (quad == 0 && wave == 0)
        *reinterpret_cast<float2*>(out + batch * SIZE + c0i) = make_float2(xa, xb);

    // ---- write X: 8 rows x 2 contiguous cols per lane (coalesced float2) ----
    float* __restrict__ Xb = out + BATCH * SIZE + (size_t)batch * SIZE * SIZE;
#pragma unroll
    for (int p = 0; p < 4; ++p) {
        const int r0 = row0 + 2 * p;
        *reinterpret_cast<float2*>(Xb + (size_t)r0 * SIZE + c0i) =
            make_float2(cA[p].x, cB[p].x);
        *reinterpret_cast<float2*>(Xb + (size_t)(r0 + 1) * SIZE + c0i) =
            make_float2(cA[p].y, cB[p].y);
    }
}

extern "C" void kernel_launch(void* const* d_in, const int* in_sizes, int n_in,
                              void* d_out, int out_size, void* d_ws, size_t ws_size,
                              hipStream_t stream) {
    const float* vec = (const float*)d_in[0];
    float* out = (float*)d_out;
    (void)in_sizes; (void)n_in; (void)d_ws; (void)ws_size; (void)out_size;

    hipLaunchKernelGGL(soft_sort_cols, dim3(BATCH * 4), dim3(256), 0, stream,
                       vec, out);
}